// Round 10
// baseline (212.930 us; speedup 1.0000x reference)
//
#include <hip/hip_runtime.h>
#include <math.h>

#define BB 4
#define LL 512
#define DD 256
#define HH 8
#define DHH 32
#define NB 12  // BUCKETS + 1 (row 11 is the zero padding row)

// K1: QKV projections. Block = (mat, 16 rows), 256 thr; thread = 4 rows x 4 cols.
// mat0 writes Qu = q/sqrt(dh)+u and Qv = q/sqrt(dh)+v. mat1 writes KT[b][h][d][k].
// mat2 writes V[b][k][d]. 384 blocks.
__global__ __launch_bounds__(256) void qkv_kernel(const float* __restrict__ x,
    const float* __restrict__ Wq, const float* __restrict__ bq,
    const float* __restrict__ Wk, const float* __restrict__ bk,
    const float* __restrict__ Wv, const float* __restrict__ bv,
    const float* __restrict__ uvec, const float* __restrict__ vvec,
    float* __restrict__ Qu, float* __restrict__ Qv,
    float* __restrict__ KT, float* __restrict__ V) {
    __shared__ float xs[16][DD];
    const int mat = blockIdx.x >> 7;          // 0=Q, 1=K, 2=V (128 tiles each)
    const int r0 = (blockIdx.x & 127) * 16;
    const int t = threadIdx.x;
    const int cg = t & 63, rg = t >> 6;       // col group (x4), row group (x4 rows)
    const int c0 = cg * 4;
    {   // stage 16 rows of x (1024 float4, 4/thread, coalesced)
        const float4* xg = (const float4*)(x + r0 * DD);
        float4* xsv = (float4*)&xs[0][0];
#pragma unroll
        for (int j = 0; j < 4; ++j) xsv[t + j * 256] = xg[t + j * 256];
    }
    __syncthreads();
    const float* W    = (mat == 0) ? Wq : (mat == 1) ? Wk : Wv;
    const float* bias = (mat == 0) ? bq : (mat == 1) ? bk : bv;
    float acc[4][4];
#pragma unroll
    for (int r = 0; r < 4; ++r)
#pragma unroll
        for (int c = 0; c < 4; ++c) acc[r][c] = bias[c0 + c];
    for (int i0 = 0; i0 < DD; i0 += 4) {
        float4 wv4[4], xv4[4];
#pragma unroll
        for (int j = 0; j < 4; ++j) wv4[j] = *(const float4*)&W[(i0 + j) * DD + c0];
#pragma unroll
        for (int r = 0; r < 4; ++r) xv4[r] = *(const float4*)&xs[rg * 4 + r][i0];
        const float* wf = (const float*)wv4;  // wf[j*4+c]
        const float* xf = (const float*)xv4;  // xf[r*4+j]
#pragma unroll
        for (int r = 0; r < 4; ++r)
#pragma unroll
            for (int j = 0; j < 4; ++j)
#pragma unroll
                for (int c = 0; c < 4; ++c)
                    acc[r][c] = fmaf(xf[r * 4 + j], wf[j * 4 + c], acc[r][c]);
    }
    if (mat == 0) {
        const float s = 0.17677669529663687f;  // 1/sqrt(DH)
        const float4 u4 = *(const float4*)&uvec[c0];
        const float4 v4 = *(const float4*)&vvec[c0];
#pragma unroll
        for (int r = 0; r < 4; ++r) {
            const int row = r0 + rg * 4 + r;
            float4 q = make_float4(acc[r][0] * s, acc[r][1] * s, acc[r][2] * s, acc[r][3] * s);
            *(float4*)&Qu[row * DD + c0] = make_float4(q.x + u4.x, q.y + u4.y, q.z + u4.z, q.w + u4.w);
            *(float4*)&Qv[row * DD + c0] = make_float4(q.x + v4.x, q.y + v4.y, q.z + v4.z, q.w + v4.w);
        }
    } else if (mat == 1) {
        const int b = r0 >> 9;                 // 16-row tiles never straddle batches
        const int kb = (r0 & 511) + rg * 4;    // 4 consecutive k
#pragma unroll
        for (int c = 0; c < 4; ++c) {
            const int col = c0 + c;
            const int h = col >> 5, dd = col & 31;
            *(float4*)&KT[((long)((b * HH + h) * DHH + dd)) * LL + kb] =
                make_float4(acc[0][c], acc[1][c], acc[2][c], acc[3][c]);
        }
    } else {
#pragma unroll
        for (int r = 0; r < 4; ++r)
            *(float4*)&V[(r0 + rg * 4 + r) * DD + c0] =
                make_float4(acc[r][0], acc[r][1], acc[r][2], acc[r][3]);
    }
}

// K2: fused rel-P + scores + softmax + attn write + CTX. Block = (b, 16q, h),
// 512 thr = 8 waves. Phase A (round-9 structure): wave w owns q rows {2w,2w+1},
// thread covers k in {4l..4l+3, 4l+256..4l+259}; K float4-coalesced from KT;
// wave-local softmax (no max-subtraction: scores bounded ~±1; masked -> e=0).
// Normalized attn goes to global AND to LDS Ss. Phase B: thread=(q,d) computes
// ctx[q][h*32+d] from Ss (b128, 2-way broadcast) x V (register-pipelined),
// killing the 33.5 MB attn HBM round-trip that ctx_out paid.
__global__ __launch_bounds__(512) void scores_ctx_kernel(const float* __restrict__ Qu,
    const float* __restrict__ Qv, const float* __restrict__ KT,
    const float* __restrict__ rel_table, const int* __restrict__ mask,
    const int* __restrict__ dist, const float* __restrict__ V,
    float* __restrict__ attn, float* __restrict__ ctx) {
    __shared__ float Qs[16][DHH];       // q + u
    __shared__ float Qv8[16][DHH];      // q + v
    __shared__ float rels[NB][DHH + 1];
    __shared__ float Ps[16][NB];
    __shared__ float Ss[16][LL];        // normalized attn tile (32 KB)
    const int blk = blockIdx.x;         // ((b*32 + qt)*8 + h)
    const int h = blk & 7;
    const int rest = blk >> 3;
    const int qt = rest & 31;
    const int b = rest >> 5;
    const int q0 = qt * 16;
    const int t = threadIdx.x;
    const int w = t >> 6, l = t & 63;

    {
        const int r = t >> 5, c = t & 31;
        Qs[r][c]  = Qu[(b * LL + q0 + r) * DD + h * DHH + c];
        Qv8[r][c] = Qv[(b * LL + q0 + r) * DD + h * DHH + c];
    }
    if (t < NB * DHH) {
        rels[t >> 5][t & 31] = rel_table[(t >> 5) * DD + h * DHH + (t & 31)];
    }
    __syncthreads();
    if (t < 16 * NB) {                  // Ps[r][bk] = dot32(Qv8[r], rels[bk])
        const int bk = t >> 4, r = t & 15;
        float a = 0.f;
#pragma unroll
        for (int d = 0; d < DHH; ++d) a = fmaf(Qv8[r][d], rels[bk][d], a);
        Ps[r][bk] = a;
    }
    __syncthreads();

    // ---- Phase A: scores + softmax ----
    const int r0 = 2 * w;               // this wave's local rows
    const long kbase = (long)(b * HH + h) * DHH * LL;
    float e0[2][4], e1[2][4];
    float sum0 = 0.f, sum1 = 0.f;
#pragma unroll
    for (int s = 0; s < 2; ++s) {
        const int k0 = 4 * l + 256 * s;
        const int4 dx0 = *(const int4*)&dist[(b * LL + q0 + r0) * LL + k0];
        const int4 dx1 = *(const int4*)&dist[(b * LL + q0 + r0 + 1) * LL + k0];
        const int4 mx0 = *(const int4*)&mask[(b * LL + q0 + r0) * LL + k0];
        const int4 mx1 = *(const int4*)&mask[(b * LL + q0 + r0 + 1) * LL + k0];
        float s0[4], s1[4];
        s0[0] = Ps[r0][dx0.x]; s0[1] = Ps[r0][dx0.y]; s0[2] = Ps[r0][dx0.z]; s0[3] = Ps[r0][dx0.w];
        s1[0] = Ps[r0 + 1][dx1.x]; s1[1] = Ps[r0 + 1][dx1.y]; s1[2] = Ps[r0 + 1][dx1.z]; s1[3] = Ps[r0 + 1][dx1.w];
#pragma unroll
        for (int d4 = 0; d4 < DHH; d4 += 4) {
            const float4 q0v = *(const float4*)&Qs[r0][d4];
            const float4 q1v = *(const float4*)&Qs[r0 + 1][d4];
            float4 kv[4];
#pragma unroll
            for (int j = 0; j < 4; ++j)
                kv[j] = *(const float4*)&KT[kbase + (long)(d4 + j) * LL + k0];
            const float* qf0 = (const float*)&q0v;
            const float* qf1 = (const float*)&q1v;
#pragma unroll
            for (int j = 0; j < 4; ++j) {
                s0[0] = fmaf(qf0[j], kv[j].x, s0[0]);
                s0[1] = fmaf(qf0[j], kv[j].y, s0[1]);
                s0[2] = fmaf(qf0[j], kv[j].z, s0[2]);
                s0[3] = fmaf(qf0[j], kv[j].w, s0[3]);
                s1[0] = fmaf(qf1[j], kv[j].x, s1[0]);
                s1[1] = fmaf(qf1[j], kv[j].y, s1[1]);
                s1[2] = fmaf(qf1[j], kv[j].z, s1[2]);
                s1[3] = fmaf(qf1[j], kv[j].w, s1[3]);
            }
        }
        e0[s][0] = mx0.x ? 0.f : __expf(s0[0]);
        e0[s][1] = mx0.y ? 0.f : __expf(s0[1]);
        e0[s][2] = mx0.z ? 0.f : __expf(s0[2]);
        e0[s][3] = mx0.w ? 0.f : __expf(s0[3]);
        e1[s][0] = mx1.x ? 0.f : __expf(s1[0]);
        e1[s][1] = mx1.y ? 0.f : __expf(s1[1]);
        e1[s][2] = mx1.z ? 0.f : __expf(s1[2]);
        e1[s][3] = mx1.w ? 0.f : __expf(s1[3]);
        sum0 += (e0[s][0] + e0[s][1]) + (e0[s][2] + e0[s][3]);
        sum1 += (e1[s][0] + e1[s][1]) + (e1[s][2] + e1[s][3]);
    }
    for (int off = 32; off > 0; off >>= 1) {
        sum0 += __shfl_xor(sum0, off);
        sum1 += __shfl_xor(sum1, off);
    }
    const float i0 = 1.0f / sum0, i1 = 1.0f / sum1;
    float* a0 = attn + ((long)(b * HH + h) * LL + q0 + r0) * LL;
    float* a1 = a0 + LL;
#pragma unroll
    for (int s = 0; s < 2; ++s) {
        const int k0 = 4 * l + 256 * s;
        const float4 o0 = make_float4(e0[s][0] * i0, e0[s][1] * i0, e0[s][2] * i0, e0[s][3] * i0);
        const float4 o1 = make_float4(e1[s][0] * i1, e1[s][1] * i1, e1[s][2] * i1, e1[s][3] * i1);
        *(float4*)&a0[k0] = o0;
        *(float4*)&a1[k0] = o1;
        *(float4*)&Ss[r0][k0] = o0;
        *(float4*)&Ss[r0 + 1][k0] = o1;
    }
    __syncthreads();

    // ---- Phase B: ctx[q][h*32+d] = sum_k Ss[q][k] * V[b][k][h*32+d] ----
    const int q = t >> 5;               // 0..15
    const int d = t & 31;
    const float* vb = V + (long)(b * LL) * DD + h * DHH + d;
    float accA = 0.f, accB = 0.f;
    float vA[8], vB[8];
    float4 pA0, pA1, pB0, pB1;
#pragma unroll
    for (int j = 0; j < 8; ++j) vA[j] = vb[j * DD];
    pA0 = *(const float4*)&Ss[q][0];
    pA1 = *(const float4*)&Ss[q][4];
    for (int k0 = 0; k0 < LL; k0 += 16) {
#pragma unroll
        for (int j = 0; j < 8; ++j) vB[j] = vb[(k0 + 8 + j) * DD];
        pB0 = *(const float4*)&Ss[q][k0 + 8];
        pB1 = *(const float4*)&Ss[q][k0 + 12];
        accA = fmaf(pA0.x, vA[0], fmaf(pA0.y, vA[1], fmaf(pA0.z, vA[2], fmaf(pA0.w, vA[3], accA))));
        accB = fmaf(pA1.x, vA[4], fmaf(pA1.y, vA[5], fmaf(pA1.z, vA[6], fmaf(pA1.w, vA[7], accB))));
        if (k0 + 16 < LL) {
#pragma unroll
            for (int j = 0; j < 8; ++j) vA[j] = vb[(k0 + 16 + j) * DD];
            pA0 = *(const float4*)&Ss[q][k0 + 16];
            pA1 = *(const float4*)&Ss[q][k0 + 20];
        }
        accA = fmaf(pB0.x, vB[0], fmaf(pB0.y, vB[1], fmaf(pB0.z, vB[2], fmaf(pB0.w, vB[3], accA))));
        accB = fmaf(pB1.x, vB[4], fmaf(pB1.y, vB[5], fmaf(pB1.z, vB[6], fmaf(pB1.w, vB[7], accB))));
    }
    ctx[(b * LL + q0 + q) * DD + h * DHH + d] = accA + accB;
}

// K3: output projection. Block = 8 rows, 256 blocks; thread = 2 rows x 4 cols.
__global__ __launch_bounds__(256) void outproj_kernel(const float* __restrict__ ctx,
    const float* __restrict__ Wo, const float* __restrict__ bo,
    float* __restrict__ out) {
    __shared__ float xs[8][DD];
    const int r0 = blockIdx.x * 8;
    const int t = threadIdx.x;
    const int cg = t & 63, rg = t >> 6;
    const int c0 = cg * 4;
    {
        const float4* xg = (const float4*)(ctx + r0 * DD);
        float4* xsv = (float4*)&xs[0][0];
        xsv[t] = xg[t];
        xsv[t + 256] = xg[t + 256];
    }
    __syncthreads();
    float acc[2][4];
#pragma unroll
    for (int r = 0; r < 2; ++r)
#pragma unroll
        for (int c = 0; c < 4; ++c) acc[r][c] = bo[c0 + c];
    for (int i0 = 0; i0 < DD; i0 += 4) {
        float4 wv4[4], xv4[2];
#pragma unroll
        for (int j = 0; j < 4; ++j) wv4[j] = *(const float4*)&Wo[(i0 + j) * DD + c0];
#pragma unroll
        for (int r = 0; r < 2; ++r) xv4[r] = *(const float4*)&xs[rg * 2 + r][i0];
        const float* wf = (const float*)wv4;
        const float* xf = (const float*)xv4;
#pragma unroll
        for (int r = 0; r < 2; ++r)
#pragma unroll
            for (int j = 0; j < 4; ++j)
#pragma unroll
                for (int c = 0; c < 4; ++c)
                    acc[r][c] = fmaf(xf[r * 4 + j], wf[j * 4 + c], acc[r][c]);
    }
#pragma unroll
    for (int r = 0; r < 2; ++r)
        *(float4*)&out[(r0 + rg * 2 + r) * DD + c0] =
            make_float4(acc[r][0], acc[r][1], acc[r][2], acc[r][3]);
}

extern "C" void kernel_launch(void* const* d_in, const int* in_sizes, int n_in,
                              void* d_out, int out_size, void* d_ws, size_t ws_size,
                              hipStream_t stream) {
    const float* x    = (const float*)d_in[0];
    const int* mk     = (const int*)d_in[1];   // jax bool -> int32
    const int* dist   = (const int*)d_in[2];
    const float* Wq = (const float*)d_in[3];
    const float* bq = (const float*)d_in[4];
    const float* Wk = (const float*)d_in[5];
    const float* bk = (const float*)d_in[6];
    const float* Wv = (const float*)d_in[7];
    const float* bv = (const float*)d_in[8];
    const float* Wo = (const float*)d_in[9];
    const float* bo = (const float*)d_in[10];
    const float* rel_table = (const float*)d_in[11];
    const float* uvec = (const float*)d_in[12];
    const float* vvec = (const float*)d_in[13];

    float* out  = (float*)d_out;                 // (B,L,D)
    float* attn = out + BB * LL * DD;            // (B,H,L,L)

    float* Qu = (float*)d_ws;                    // q/sqrt(dh) + u
    float* Qv = Qu + BB * LL * DD;               // q/sqrt(dh) + v
    float* KT = Qv + BB * LL * DD;               // [B][H][DH][L]
    float* V  = KT + BB * LL * DD;               // [B][L][D]
    float* C  = V + BB * LL * DD;                // ctx (B,L,D); 10.5 MB ws total

    qkv_kernel<<<3 * 128, 256, 0, stream>>>(x, Wq, bq, Wk, bk, Wv, bv, uvec, vvec,
                                            Qu, Qv, KT, V);
    scores_ctx_kernel<<<BB * (LL / 16) * HH, 512, 0, stream>>>(Qu, Qv, KT, rel_table,
                                                               mk, dist, V, attn, C);
    outproj_kernel<<<BB * LL / 8, 256, 0, stream>>>(C, Wo, bo, out);
}

// Round 11
// 186.895 us; speedup vs baseline: 1.1393x; 1.1393x over previous
//
#include <hip/hip_runtime.h>
#include <math.h>

#define BB 4
#define LL 512
#define DD 256
#define HH 8
#define DHH 32
#define NB 12  // BUCKETS + 1 (row 11 is the zero padding row)

// K1: QKV projections (round-9 structure: 8-row tiles, 768 blocks = 3 blocks/CU).
// Thread = 2 rows x 4 cols. mat0 writes Qu=q/sqrt(dh)+u, Qv=q/sqrt(dh)+v;
// mat1 writes KT[b][h][d][k]; mat2 writes V[b][k][d].
__global__ __launch_bounds__(256) void qkv_kernel(const float* __restrict__ x,
    const float* __restrict__ Wq, const float* __restrict__ bq,
    const float* __restrict__ Wk, const float* __restrict__ bk,
    const float* __restrict__ Wv, const float* __restrict__ bv,
    const float* __restrict__ uvec, const float* __restrict__ vvec,
    float* __restrict__ Qu, float* __restrict__ Qv,
    float* __restrict__ KT, float* __restrict__ V) {
    __shared__ float xs[8][DD];
    const int mat = blockIdx.x >> 8;          // 0=Q, 1=K, 2=V
    const int r0 = (blockIdx.x & 255) * 8;
    const int t = threadIdx.x;
    const int cg = t & 63, rg = t >> 6;
    const int c0 = cg * 4;
    {
        const float4* xg = (const float4*)(x + r0 * DD);
        float4* xsv = (float4*)&xs[0][0];
        xsv[t] = xg[t];
        xsv[t + 256] = xg[t + 256];
    }
    __syncthreads();
    const float* W    = (mat == 0) ? Wq : (mat == 1) ? Wk : Wv;
    const float* bias = (mat == 0) ? bq : (mat == 1) ? bk : bv;
    float acc[2][4];
#pragma unroll
    for (int r = 0; r < 2; ++r)
#pragma unroll
        for (int c = 0; c < 4; ++c) acc[r][c] = bias[c0 + c];
    for (int i0 = 0; i0 < DD; i0 += 4) {
        float4 wv4[4], xv4[2];
#pragma unroll
        for (int j = 0; j < 4; ++j) wv4[j] = *(const float4*)&W[(i0 + j) * DD + c0];
#pragma unroll
        for (int r = 0; r < 2; ++r) xv4[r] = *(const float4*)&xs[rg * 2 + r][i0];
        const float* wf = (const float*)wv4;
        const float* xf = (const float*)xv4;
#pragma unroll
        for (int r = 0; r < 2; ++r)
#pragma unroll
            for (int j = 0; j < 4; ++j)
#pragma unroll
                for (int c = 0; c < 4; ++c)
                    acc[r][c] = fmaf(xf[r * 4 + j], wf[j * 4 + c], acc[r][c]);
    }
    if (mat == 0) {
        const float s = 0.17677669529663687f;  // 1/sqrt(DH)
        const float4 u4 = *(const float4*)&uvec[c0];
        const float4 v4 = *(const float4*)&vvec[c0];
#pragma unroll
        for (int r = 0; r < 2; ++r) {
            const int row = r0 + rg * 2 + r;
            float4 q = make_float4(acc[r][0] * s, acc[r][1] * s, acc[r][2] * s, acc[r][3] * s);
            *(float4*)&Qu[row * DD + c0] = make_float4(q.x + u4.x, q.y + u4.y, q.z + u4.z, q.w + u4.w);
            *(float4*)&Qv[row * DD + c0] = make_float4(q.x + v4.x, q.y + v4.y, q.z + v4.z, q.w + v4.w);
        }
    } else if (mat == 1) {
        const int b = r0 >> 9;
        const int kb = (r0 & 511) + rg * 2;
#pragma unroll
        for (int c = 0; c < 4; ++c) {
            const int col = c0 + c;
            const int h = col >> 5, dd = col & 31;
            float* p = KT + ((long)((b * HH + h) * DHH + dd)) * LL + kb;
            p[0] = acc[0][c];
            p[1] = acc[1][c];
        }
    } else {
#pragma unroll
        for (int r = 0; r < 2; ++r)
            *(float4*)&V[(r0 + rg * 2 + r) * DD + c0] =
                make_float4(acc[r][0], acc[r][1], acc[r][2], acc[r][3]);
    }
}

// K2: fused rel-P + scores + softmax + attn write + ctx.
// Phase A (round-9/10 structure): wave w owns q rows {2w,2w+1}; K float4 from KT;
// wave-local softmax (no max-subtraction: scores bounded ~±1; masked -> e=0).
// Attn tile also kept in LDS Ss[16][4][132] (chunked+padded: phase-B (q,ks) reads
// land on 8 distinct bank-quads, conflict-free).
// Phase B: thread=(q, ks in 4, dg in 8): k-split dot, float4 V loads (4 full lines
// per wave instr), A/B register pipeline, LDS partial-reduce over ks.
__global__ __launch_bounds__(512, 6) void scores_ctx_kernel(const float* __restrict__ Qu,
    const float* __restrict__ Qv, const float* __restrict__ KT,
    const float* __restrict__ rel_table, const int* __restrict__ mask,
    const int* __restrict__ dist, const float* __restrict__ V,
    float* __restrict__ attn, float* __restrict__ ctx) {
    __shared__ float Qs[16][DHH];
    __shared__ float Qv8[16][DHH];
    __shared__ float rels[NB][DHH + 1];
    __shared__ float Ps[16][NB];
    __shared__ float Ss[16][4][132];    // attn tile, 4 k-chunks of 128 + pad 4
    __shared__ float4 Cp[512];          // phase-B partials
    const int blk = blockIdx.x;         // ((b*32 + qt)*8 + h)
    const int h = blk & 7;
    const int rest = blk >> 3;
    const int qt = rest & 31;
    const int b = rest >> 5;
    const int q0 = qt * 16;
    const int t = threadIdx.x;
    const int w = t >> 6, l = t & 63;

    {
        const int r = t >> 5, c = t & 31;
        Qs[r][c]  = Qu[(b * LL + q0 + r) * DD + h * DHH + c];
        Qv8[r][c] = Qv[(b * LL + q0 + r) * DD + h * DHH + c];
    }
    if (t < NB * DHH) {
        rels[t >> 5][t & 31] = rel_table[(t >> 5) * DD + h * DHH + (t & 31)];
    }
    __syncthreads();
    if (t < 16 * NB) {                  // Ps[r][bk] = dot32(Qv8[r], rels[bk])
        const int bk = t >> 4, r = t & 15;
        float a = 0.f;
#pragma unroll
        for (int d = 0; d < DHH; ++d) a = fmaf(Qv8[r][d], rels[bk][d], a);
        Ps[r][bk] = a;
    }
    __syncthreads();

    // ---- Phase A ----
    const int r0 = 2 * w;
    const long kbase = (long)(b * HH + h) * DHH * LL;
    float e0[2][4], e1[2][4];
    float sum0 = 0.f, sum1 = 0.f;
#pragma unroll
    for (int s = 0; s < 2; ++s) {
        const int k0 = 4 * l + 256 * s;
        const int4 dx0 = *(const int4*)&dist[(b * LL + q0 + r0) * LL + k0];
        const int4 dx1 = *(const int4*)&dist[(b * LL + q0 + r0 + 1) * LL + k0];
        const int4 mx0 = *(const int4*)&mask[(b * LL + q0 + r0) * LL + k0];
        const int4 mx1 = *(const int4*)&mask[(b * LL + q0 + r0 + 1) * LL + k0];
        float s0[4], s1[4];
        s0[0] = Ps[r0][dx0.x]; s0[1] = Ps[r0][dx0.y]; s0[2] = Ps[r0][dx0.z]; s0[3] = Ps[r0][dx0.w];
        s1[0] = Ps[r0 + 1][dx1.x]; s1[1] = Ps[r0 + 1][dx1.y]; s1[2] = Ps[r0 + 1][dx1.z]; s1[3] = Ps[r0 + 1][dx1.w];
#pragma unroll
        for (int d4 = 0; d4 < DHH; d4 += 4) {
            const float4 q0v = *(const float4*)&Qs[r0][d4];
            const float4 q1v = *(const float4*)&Qs[r0 + 1][d4];
            float4 kv[4];
#pragma unroll
            for (int j = 0; j < 4; ++j)
                kv[j] = *(const float4*)&KT[kbase + (long)(d4 + j) * LL + k0];
            const float* qf0 = (const float*)&q0v;
            const float* qf1 = (const float*)&q1v;
#pragma unroll
            for (int j = 0; j < 4; ++j) {
                s0[0] = fmaf(qf0[j], kv[j].x, s0[0]);
                s0[1] = fmaf(qf0[j], kv[j].y, s0[1]);
                s0[2] = fmaf(qf0[j], kv[j].z, s0[2]);
                s0[3] = fmaf(qf0[j], kv[j].w, s0[3]);
                s1[0] = fmaf(qf1[j], kv[j].x, s1[0]);
                s1[1] = fmaf(qf1[j], kv[j].y, s1[1]);
                s1[2] = fmaf(qf1[j], kv[j].z, s1[2]);
                s1[3] = fmaf(qf1[j], kv[j].w, s1[3]);
            }
        }
        e0[s][0] = mx0.x ? 0.f : __expf(s0[0]);
        e0[s][1] = mx0.y ? 0.f : __expf(s0[1]);
        e0[s][2] = mx0.z ? 0.f : __expf(s0[2]);
        e0[s][3] = mx0.w ? 0.f : __expf(s0[3]);
        e1[s][0] = mx1.x ? 0.f : __expf(s1[0]);
        e1[s][1] = mx1.y ? 0.f : __expf(s1[1]);
        e1[s][2] = mx1.z ? 0.f : __expf(s1[2]);
        e1[s][3] = mx1.w ? 0.f : __expf(s1[3]);
        sum0 += (e0[s][0] + e0[s][1]) + (e0[s][2] + e0[s][3]);
        sum1 += (e1[s][0] + e1[s][1]) + (e1[s][2] + e1[s][3]);
    }
    for (int off = 32; off > 0; off >>= 1) {
        sum0 += __shfl_xor(sum0, off);
        sum1 += __shfl_xor(sum1, off);
    }
    const float i0 = 1.0f / sum0, i1 = 1.0f / sum1;
    float* a0 = attn + ((long)(b * HH + h) * LL + q0 + r0) * LL;
    float* a1 = a0 + LL;
#pragma unroll
    for (int s = 0; s < 2; ++s) {
        const int k0 = 4 * l + 256 * s;
        const int ch = k0 >> 7, off = k0 & 127;
        const float4 o0 = make_float4(e0[s][0] * i0, e0[s][1] * i0, e0[s][2] * i0, e0[s][3] * i0);
        const float4 o1 = make_float4(e1[s][0] * i1, e1[s][1] * i1, e1[s][2] * i1, e1[s][3] * i1);
        *(float4*)&a0[k0] = o0;
        *(float4*)&a1[k0] = o1;
        *(float4*)&Ss[r0][ch][off] = o0;
        *(float4*)&Ss[r0 + 1][ch][off] = o1;
    }
    __syncthreads();

    // ---- Phase B: ctx[q][h*32+dg*4..+3] partial over k-quarter ks ----
    const int qB = t >> 5;              // 0..15
    const int ks = (t >> 3) & 3;        // k-quarter
    const int dg = t & 7;               // d-group of 4
    const float* vb = V + ((long)(b * LL + ks * 128)) * DD + h * DHH + dg * 4;
    float4 acc = make_float4(0.f, 0.f, 0.f, 0.f);
    float4 vA[4], vB[4];
    float4 aA, aB;
#pragma unroll
    for (int j = 0; j < 4; ++j) vA[j] = *(const float4*)&vb[j * DD];
    aA = *(const float4*)&Ss[qB][ks][0];
    for (int kk = 0; kk < 128; kk += 8) {
#pragma unroll
        for (int j = 0; j < 4; ++j) vB[j] = *(const float4*)&vb[(kk + 4 + j) * DD];
        aB = *(const float4*)&Ss[qB][ks][kk + 4];
        acc.x = fmaf(aA.x, vA[0].x, fmaf(aA.y, vA[1].x, fmaf(aA.z, vA[2].x, fmaf(aA.w, vA[3].x, acc.x))));
        acc.y = fmaf(aA.x, vA[0].y, fmaf(aA.y, vA[1].y, fmaf(aA.z, vA[2].y, fmaf(aA.w, vA[3].y, acc.y))));
        acc.z = fmaf(aA.x, vA[0].z, fmaf(aA.y, vA[1].z, fmaf(aA.z, vA[2].z, fmaf(aA.w, vA[3].z, acc.z))));
        acc.w = fmaf(aA.x, vA[0].w, fmaf(aA.y, vA[1].w, fmaf(aA.z, vA[2].w, fmaf(aA.w, vA[3].w, acc.w))));
        if (kk + 8 < 128) {
#pragma unroll
            for (int j = 0; j < 4; ++j) vA[j] = *(const float4*)&vb[(kk + 8 + j) * DD];
            aA = *(const float4*)&Ss[qB][ks][kk + 8];
        }
        acc.x = fmaf(aB.x, vB[0].x, fmaf(aB.y, vB[1].x, fmaf(aB.z, vB[2].x, fmaf(aB.w, vB[3].x, acc.x))));
        acc.y = fmaf(aB.x, vB[0].y, fmaf(aB.y, vB[1].y, fmaf(aB.z, vB[2].y, fmaf(aB.w, vB[3].y, acc.y))));
        acc.z = fmaf(aB.x, vB[0].z, fmaf(aB.y, vB[1].z, fmaf(aB.z, vB[2].z, fmaf(aB.w, vB[3].z, acc.z))));
        acc.w = fmaf(aB.x, vB[0].w, fmaf(aB.y, vB[1].w, fmaf(aB.z, vB[2].w, fmaf(aB.w, vB[3].w, acc.w))));
    }
    Cp[t] = acc;
    __syncthreads();
    if (ks == 0) {
        const float4 c0 = Cp[t];
        const float4 c1 = Cp[t + 8];
        const float4 c2 = Cp[t + 16];
        const float4 c3 = Cp[t + 24];
        const float4 r = make_float4((c0.x + c1.x) + (c2.x + c3.x),
                                     (c0.y + c1.y) + (c2.y + c3.y),
                                     (c0.z + c1.z) + (c2.z + c3.z),
                                     (c0.w + c1.w) + (c2.w + c3.w));
        *(float4*)&ctx[(b * LL + q0 + qB) * DD + h * DHH + dg * 4] = r;
    }
}

// K3: output projection. Block = 4 rows (512 blocks = 2/CU); thread = 1 row x 4 cols.
// 8-deep W float4 pipeline; x row via free LDS broadcast.
__global__ __launch_bounds__(256) void outproj_kernel(const float* __restrict__ ctx,
    const float* __restrict__ Wo, const float* __restrict__ bo,
    float* __restrict__ out) {
    __shared__ float xs[4][DD];
    const int r0 = blockIdx.x * 4;
    const int t = threadIdx.x;
    const int rg = t >> 6;
    const int c0 = (t & 63) * 4;
    ((float4*)&xs[0][0])[t] = ((const float4*)(ctx + r0 * DD))[t];
    __syncthreads();
    float4 acc = *(const float4*)&bo[c0];
    for (int i0 = 0; i0 < DD; i0 += 8) {
        float4 wv[8];
#pragma unroll
        for (int j = 0; j < 8; ++j) wv[j] = *(const float4*)&Wo[(i0 + j) * DD + c0];
        const float4 x0 = *(const float4*)&xs[rg][i0];
        const float4 x1 = *(const float4*)&xs[rg][i0 + 4];
        const float* xf0 = (const float*)&x0;
        const float* xf1 = (const float*)&x1;
#pragma unroll
        for (int j = 0; j < 4; ++j) {
            acc.x = fmaf(xf0[j], wv[j].x, acc.x);
            acc.y = fmaf(xf0[j], wv[j].y, acc.y);
            acc.z = fmaf(xf0[j], wv[j].z, acc.z);
            acc.w = fmaf(xf0[j], wv[j].w, acc.w);
        }
#pragma unroll
        for (int j = 0; j < 4; ++j) {
            acc.x = fmaf(xf1[j], wv[j + 4].x, acc.x);
            acc.y = fmaf(xf1[j], wv[j + 4].y, acc.y);
            acc.z = fmaf(xf1[j], wv[j + 4].z, acc.z);
            acc.w = fmaf(xf1[j], wv[j + 4].w, acc.w);
        }
    }
    *(float4*)&out[(r0 + rg) * DD + c0] = acc;
}

extern "C" void kernel_launch(void* const* d_in, const int* in_sizes, int n_in,
                              void* d_out, int out_size, void* d_ws, size_t ws_size,
                              hipStream_t stream) {
    const float* x    = (const float*)d_in[0];
    const int* mk     = (const int*)d_in[1];   // jax bool -> int32
    const int* dist   = (const int*)d_in[2];
    const float* Wq = (const float*)d_in[3];
    const float* bq = (const float*)d_in[4];
    const float* Wk = (const float*)d_in[5];
    const float* bk = (const float*)d_in[6];
    const float* Wv = (const float*)d_in[7];
    const float* bv = (const float*)d_in[8];
    const float* Wo = (const float*)d_in[9];
    const float* bo = (const float*)d_in[10];
    const float* rel_table = (const float*)d_in[11];
    const float* uvec = (const float*)d_in[12];
    const float* vvec = (const float*)d_in[13];

    float* out  = (float*)d_out;                 // (B,L,D)
    float* attn = out + BB * LL * DD;            // (B,H,L,L)

    float* Qu = (float*)d_ws;                    // q/sqrt(dh) + u
    float* Qv = Qu + BB * LL * DD;               // q/sqrt(dh) + v
    float* KT = Qv + BB * LL * DD;               // [B][H][DH][L]
    float* V  = KT + BB * LL * DD;               // [B][L][D]
    float* C  = V + BB * LL * DD;                // ctx (B,L,D); 10.5 MB ws total

    qkv_kernel<<<3 * 256, 256, 0, stream>>>(x, Wq, bq, Wk, bk, Wv, bv, uvec, vvec,
                                            Qu, Qv, KT, V);
    scores_ctx_kernel<<<BB * (LL / 16) * HH, 512, 0, stream>>>(Qu, Qv, KT, rel_table,
                                                               mk, dist, V, attn, C);
    outproj_kernel<<<BB * LL / 4, 256, 0, stream>>>(C, Wo, bo, out);
}

// Round 12
// 179.754 us; speedup vs baseline: 1.1846x; 1.0397x over previous
//
#include <hip/hip_runtime.h>
#include <math.h>

#define BB 4
#define LL 512
#define DD 256
#define HH 8
#define DHH 32
#define NB 12  // BUCKETS + 1 (row 11 is the zero padding row)

// K1: QKV projections (8-row tiles, 768 blocks = 3 blocks/CU).
// Thread = 2 rows x 4 cols. mat0 writes Qu=q/sqrt(dh)+u, Qv=q/sqrt(dh)+v;
// mat1 writes KT[b][h][d][k]; mat2 writes V[b][k][d].
__global__ __launch_bounds__(256) void qkv_kernel(const float* __restrict__ x,
    const float* __restrict__ Wq, const float* __restrict__ bq,
    const float* __restrict__ Wk, const float* __restrict__ bk,
    const float* __restrict__ Wv, const float* __restrict__ bv,
    const float* __restrict__ uvec, const float* __restrict__ vvec,
    float* __restrict__ Qu, float* __restrict__ Qv,
    float* __restrict__ KT, float* __restrict__ V) {
    __shared__ float xs[8][DD];
    const int mat = blockIdx.x >> 8;          // 0=Q, 1=K, 2=V
    const int r0 = (blockIdx.x & 255) * 8;
    const int t = threadIdx.x;
    const int cg = t & 63, rg = t >> 6;
    const int c0 = cg * 4;
    {
        const float4* xg = (const float4*)(x + r0 * DD);
        float4* xsv = (float4*)&xs[0][0];
        xsv[t] = xg[t];
        xsv[t + 256] = xg[t + 256];
    }
    __syncthreads();
    const float* W    = (mat == 0) ? Wq : (mat == 1) ? Wk : Wv;
    const float* bias = (mat == 0) ? bq : (mat == 1) ? bk : bv;
    float acc[2][4];
#pragma unroll
    for (int r = 0; r < 2; ++r)
#pragma unroll
        for (int c = 0; c < 4; ++c) acc[r][c] = bias[c0 + c];
    for (int i0 = 0; i0 < DD; i0 += 4) {
        float4 wv4[4], xv4[2];
#pragma unroll
        for (int j = 0; j < 4; ++j) wv4[j] = *(const float4*)&W[(i0 + j) * DD + c0];
#pragma unroll
        for (int r = 0; r < 2; ++r) xv4[r] = *(const float4*)&xs[rg * 2 + r][i0];
        const float* wf = (const float*)wv4;
        const float* xf = (const float*)xv4;
#pragma unroll
        for (int r = 0; r < 2; ++r)
#pragma unroll
            for (int j = 0; j < 4; ++j)
#pragma unroll
                for (int c = 0; c < 4; ++c)
                    acc[r][c] = fmaf(xf[r * 4 + j], wf[j * 4 + c], acc[r][c]);
    }
    if (mat == 0) {
        const float s = 0.17677669529663687f;  // 1/sqrt(DH)
        const float4 u4 = *(const float4*)&uvec[c0];
        const float4 v4 = *(const float4*)&vvec[c0];
#pragma unroll
        for (int r = 0; r < 2; ++r) {
            const int row = r0 + rg * 2 + r;
            float4 q = make_float4(acc[r][0] * s, acc[r][1] * s, acc[r][2] * s, acc[r][3] * s);
            *(float4*)&Qu[row * DD + c0] = make_float4(q.x + u4.x, q.y + u4.y, q.z + u4.z, q.w + u4.w);
            *(float4*)&Qv[row * DD + c0] = make_float4(q.x + v4.x, q.y + v4.y, q.z + v4.z, q.w + v4.w);
        }
    } else if (mat == 1) {
        const int b = r0 >> 9;
        const int kb = (r0 & 511) + rg * 2;
#pragma unroll
        for (int c = 0; c < 4; ++c) {
            const int col = c0 + c;
            const int h = col >> 5, dd = col & 31;
            float* p = KT + ((long)((b * HH + h) * DHH + dd)) * LL + kb;
            p[0] = acc[0][c];
            p[1] = acc[1][c];
        }
    } else {
#pragma unroll
        for (int r = 0; r < 2; ++r)
            *(float4*)&V[(r0 + rg * 2 + r) * DD + c0] =
                make_float4(acc[r][0], acc[r][1], acc[r][2], acc[r][3]);
    }
}

// K2: fused rel-P + scores + softmax + attn write + ctx.
// Phase A: wave w owns q rows {2w,2w+1}; K loads batched 8-deep (in-flight MLP);
// no max-subtraction (scores bounded ~±1; masked -> e=0 exactly).
// Phase B: V staged per 128-k chunk into LDS Vs[32][133] (pad 133: b128 reads
// conflict-free since gcd(5,32)=1); thread=(q,d) streams Ss/Vs via b128 along k.
// V global traffic per block: 64 KB (was 1 MB).
__global__ __launch_bounds__(512, 4) void scores_ctx_kernel(const float* __restrict__ Qu,
    const float* __restrict__ Qv, const float* __restrict__ KT,
    const float* __restrict__ rel_table, const int* __restrict__ mask,
    const int* __restrict__ dist, const float* __restrict__ V,
    float* __restrict__ attn, float* __restrict__ ctx) {
    __shared__ float Qs[16][DHH];
    __shared__ float Qv8[16][DHH];
    __shared__ float rels[NB][DHH + 1];
    __shared__ float Ps[16][NB];
    __shared__ float Ss[16][4][132];    // attn tile, 4 k-chunks of 128 (+pad)
    __shared__ float Vs[DHH][133];      // V chunk, transposed [d][k] (+pad)
    const int blk = blockIdx.x;         // ((b*32 + qt)*8 + h)
    const int h = blk & 7;
    const int rest = blk >> 3;
    const int qt = rest & 31;
    const int b = rest >> 5;
    const int q0 = qt * 16;
    const int t = threadIdx.x;
    const int w = t >> 6, l = t & 63;

    {
        const int r = t >> 5, c = t & 31;
        Qs[r][c]  = Qu[(b * LL + q0 + r) * DD + h * DHH + c];
        Qv8[r][c] = Qv[(b * LL + q0 + r) * DD + h * DHH + c];
    }
    if (t < NB * DHH) {
        rels[t >> 5][t & 31] = rel_table[(t >> 5) * DD + h * DHH + (t & 31)];
    }
    __syncthreads();
    if (t < 16 * NB) {                  // Ps[r][bk] = dot32(Qv8[r], rels[bk])
        const int bk = t >> 4, r = t & 15;
        float a = 0.f;
#pragma unroll
        for (int d = 0; d < DHH; ++d) a = fmaf(Qv8[r][d], rels[bk][d], a);
        Ps[r][bk] = a;
    }
    __syncthreads();

    // ---- Phase A: scores + softmax for this wave's 2 q rows ----
    const int r0 = 2 * w;
    const long kbase = (long)(b * HH + h) * DHH * LL;
    float e0[2][4], e1[2][4];
    float sum0 = 0.f, sum1 = 0.f;
#pragma unroll
    for (int s = 0; s < 2; ++s) {
        const int k0 = 4 * l + 256 * s;
        const int4 dx0 = *(const int4*)&dist[(b * LL + q0 + r0) * LL + k0];
        const int4 dx1 = *(const int4*)&dist[(b * LL + q0 + r0 + 1) * LL + k0];
        const int4 mx0 = *(const int4*)&mask[(b * LL + q0 + r0) * LL + k0];
        const int4 mx1 = *(const int4*)&mask[(b * LL + q0 + r0 + 1) * LL + k0];
        float s0[4], s1[4];
        s0[0] = Ps[r0][dx0.x]; s0[1] = Ps[r0][dx0.y]; s0[2] = Ps[r0][dx0.z]; s0[3] = Ps[r0][dx0.w];
        s1[0] = Ps[r0 + 1][dx1.x]; s1[1] = Ps[r0 + 1][dx1.y]; s1[2] = Ps[r0 + 1][dx1.z]; s1[3] = Ps[r0 + 1][dx1.w];
#pragma unroll
        for (int d8 = 0; d8 < DHH; d8 += 8) {
            float4 kv[8];                        // 8 loads in flight
#pragma unroll
            for (int j = 0; j < 8; ++j)
                kv[j] = *(const float4*)&KT[kbase + (long)(d8 + j) * LL + k0];
            const float4 q0a = *(const float4*)&Qs[r0][d8];
            const float4 q0b = *(const float4*)&Qs[r0][d8 + 4];
            const float4 q1a = *(const float4*)&Qs[r0 + 1][d8];
            const float4 q1b = *(const float4*)&Qs[r0 + 1][d8 + 4];
            const float* qa0 = (const float*)&q0a;
            const float* qb0 = (const float*)&q0b;
            const float* qa1 = (const float*)&q1a;
            const float* qb1 = (const float*)&q1b;
#pragma unroll
            for (int j = 0; j < 4; ++j) {
                s0[0] = fmaf(qa0[j], kv[j].x, s0[0]);
                s0[1] = fmaf(qa0[j], kv[j].y, s0[1]);
                s0[2] = fmaf(qa0[j], kv[j].z, s0[2]);
                s0[3] = fmaf(qa0[j], kv[j].w, s0[3]);
                s1[0] = fmaf(qa1[j], kv[j].x, s1[0]);
                s1[1] = fmaf(qa1[j], kv[j].y, s1[1]);
                s1[2] = fmaf(qa1[j], kv[j].z, s1[2]);
                s1[3] = fmaf(qa1[j], kv[j].w, s1[3]);
            }
#pragma unroll
            for (int j = 0; j < 4; ++j) {
                s0[0] = fmaf(qb0[j], kv[j + 4].x, s0[0]);
                s0[1] = fmaf(qb0[j], kv[j + 4].y, s0[1]);
                s0[2] = fmaf(qb0[j], kv[j + 4].z, s0[2]);
                s0[3] = fmaf(qb0[j], kv[j + 4].w, s0[3]);
                s1[0] = fmaf(qb1[j], kv[j + 4].x, s1[0]);
                s1[1] = fmaf(qb1[j], kv[j + 4].y, s1[1]);
                s1[2] = fmaf(qb1[j], kv[j + 4].z, s1[2]);
                s1[3] = fmaf(qb1[j], kv[j + 4].w, s1[3]);
            }
        }
        e0[s][0] = mx0.x ? 0.f : __expf(s0[0]);
        e0[s][1] = mx0.y ? 0.f : __expf(s0[1]);
        e0[s][2] = mx0.z ? 0.f : __expf(s0[2]);
        e0[s][3] = mx0.w ? 0.f : __expf(s0[3]);
        e1[s][0] = mx1.x ? 0.f : __expf(s1[0]);
        e1[s][1] = mx1.y ? 0.f : __expf(s1[1]);
        e1[s][2] = mx1.z ? 0.f : __expf(s1[2]);
        e1[s][3] = mx1.w ? 0.f : __expf(s1[3]);
        sum0 += (e0[s][0] + e0[s][1]) + (e0[s][2] + e0[s][3]);
        sum1 += (e1[s][0] + e1[s][1]) + (e1[s][2] + e1[s][3]);
    }
    for (int off = 32; off > 0; off >>= 1) {
        sum0 += __shfl_xor(sum0, off);
        sum1 += __shfl_xor(sum1, off);
    }
    const float i0 = 1.0f / sum0, i1 = 1.0f / sum1;
    float* a0 = attn + ((long)(b * HH + h) * LL + q0 + r0) * LL;
    float* a1 = a0 + LL;
#pragma unroll
    for (int s = 0; s < 2; ++s) {
        const int k0 = 4 * l + 256 * s;
        const int ch = k0 >> 7, off = k0 & 127;
        const float4 o0 = make_float4(e0[s][0] * i0, e0[s][1] * i0, e0[s][2] * i0, e0[s][3] * i0);
        const float4 o1 = make_float4(e1[s][0] * i1, e1[s][1] * i1, e1[s][2] * i1, e1[s][3] * i1);
        *(float4*)&a0[k0] = o0;
        *(float4*)&a1[k0] = o1;
        *(float4*)&Ss[r0][ch][off] = o0;
        *(float4*)&Ss[r0 + 1][ch][off] = o1;
    }

    // ---- Phase B: ctx via LDS-staged V chunks ----
    const int qB = t >> 5;              // 0..15
    const int dB = t & 31;
    const int kkS = t >> 2;             // staging row 0..127
    const int dqS = (t & 3) * 8;        // staging d-group of 8
    float acc = 0.f;
    for (int c = 0; c < 4; ++c) {
        __syncthreads();                // prev compute done (and Ss ready at c=0)
        {   // stage V[b][c*128+kk][h*32+dq..dq+7] -> Vs[d][kk] (transposed)
            const float* vg = V + ((long)(b * LL + c * 128 + kkS)) * DD + h * DHH + dqS;
            const float4 va = *(const float4*)&vg[0];
            const float4 vb4 = *(const float4*)&vg[4];
            Vs[dqS + 0][kkS] = va.x;  Vs[dqS + 1][kkS] = va.y;
            Vs[dqS + 2][kkS] = va.z;  Vs[dqS + 3][kkS] = va.w;
            Vs[dqS + 4][kkS] = vb4.x; Vs[dqS + 5][kkS] = vb4.y;
            Vs[dqS + 6][kkS] = vb4.z; Vs[dqS + 7][kkS] = vb4.w;
        }
        __syncthreads();
#pragma unroll
        for (int j = 0; j < 32; ++j) {  // 4 k per iter
            const float4 sv = *(const float4*)&Ss[qB][c][4 * j];   // wave-broadcast
            const float4 vv = *(const float4*)&Vs[dB][4 * j];      // conflict-free (pad 133)
            acc = fmaf(sv.x, vv.x, fmaf(sv.y, vv.y, fmaf(sv.z, vv.z, fmaf(sv.w, vv.w, acc))));
        }
    }
    ctx[(b * LL + q0 + qB) * DD + h * DHH + dB] = acc;
}

// K3: output projection. Block = 4 rows (512 blocks); thread = 1 row x 4 cols.
__global__ __launch_bounds__(256) void outproj_kernel(const float* __restrict__ ctx,
    const float* __restrict__ Wo, const float* __restrict__ bo,
    float* __restrict__ out) {
    __shared__ float xs[4][DD];
    const int r0 = blockIdx.x * 4;
    const int t = threadIdx.x;
    const int rg = t >> 6;
    const int c0 = (t & 63) * 4;
    ((float4*)&xs[0][0])[t] = ((const float4*)(ctx + r0 * DD))[t];
    __syncthreads();
    float4 acc = *(const float4*)&bo[c0];
    for (int i0 = 0; i0 < DD; i0 += 8) {
        float4 wv[8];
#pragma unroll
        for (int j = 0; j < 8; ++j) wv[j] = *(const float4*)&Wo[(i0 + j) * DD + c0];
        const float4 x0 = *(const float4*)&xs[rg][i0];
        const float4 x1 = *(const float4*)&xs[rg][i0 + 4];
        const float* xf0 = (const float*)&x0;
        const float* xf1 = (const float*)&x1;
#pragma unroll
        for (int j = 0; j < 4; ++j) {
            acc.x = fmaf(xf0[j], wv[j].x, acc.x);
            acc.y = fmaf(xf0[j], wv[j].y, acc.y);
            acc.z = fmaf(xf0[j], wv[j].z, acc.z);
            acc.w = fmaf(xf0[j], wv[j].w, acc.w);
        }
#pragma unroll
        for (int j = 0; j < 4; ++j) {
            acc.x = fmaf(xf1[j], wv[j + 4].x, acc.x);
            acc.y = fmaf(xf1[j], wv[j + 4].y, acc.y);
            acc.z = fmaf(xf1[j], wv[j + 4].z, acc.z);
            acc.w = fmaf(xf1[j], wv[j + 4].w, acc.w);
        }
    }
    *(float4*)&out[(r0 + rg) * DD + c0] = acc;
}

extern "C" void kernel_launch(void* const* d_in, const int* in_sizes, int n_in,
                              void* d_out, int out_size, void* d_ws, size_t ws_size,
                              hipStream_t stream) {
    const float* x    = (const float*)d_in[0];
    const int* mk     = (const int*)d_in[1];   // jax bool -> int32
    const int* dist   = (const int*)d_in[2];
    const float* Wq = (const float*)d_in[3];
    const float* bq = (const float*)d_in[4];
    const float* Wk = (const float*)d_in[5];
    const float* bk = (const float*)d_in[6];
    const float* Wv = (const float*)d_in[7];
    const float* bv = (const float*)d_in[8];
    const float* Wo = (const float*)d_in[9];
    const float* bo = (const float*)d_in[10];
    const float* rel_table = (const float*)d_in[11];
    const float* uvec = (const float*)d_in[12];
    const float* vvec = (const float*)d_in[13];

    float* out  = (float*)d_out;                 // (B,L,D)
    float* attn = out + BB * LL * DD;            // (B,H,L,L)

    float* Qu = (float*)d_ws;                    // q/sqrt(dh) + u
    float* Qv = Qu + BB * LL * DD;               // q/sqrt(dh) + v
    float* KT = Qv + BB * LL * DD;               // [B][H][DH][L]
    float* V  = KT + BB * LL * DD;               // [B][L][D]
    float* C  = V + BB * LL * DD;                // ctx (B,L,D); 10.5 MB ws total

    qkv_kernel<<<3 * 256, 256, 0, stream>>>(x, Wq, bq, Wk, bk, Wv, bv, uvec, vvec,
                                            Qu, Qv, KT, V);
    scores_ctx_kernel<<<BB * (LL / 16) * HH, 512, 0, stream>>>(Qu, Qv, KT, rel_table,
                                                               mk, dist, V, attn, C);
    outproj_kernel<<<BB * LL / 4, 256, 0, stream>>>(C, Wo, bo, out);
}